// Round 1
// baseline (160.943 us; speedup 1.0000x reference)
//
#include <hip/hip_runtime.h>
#include <hip/hip_bf16.h>

// Problem constants (from reference setup_inputs)
#define B_   8
#define T_   4096
#define D_   1024
#define DENT 256
#define F_   1280          // D_ + DENT
#define E_   32            // MAX_EVENTS
#define TVOCAB 512

// ---------------------------------------------------------------------------
// Kernel 1: event selection. One block per batch.
// Replicates: surprise = max|z| over 8; mask = surprise > 2.0; fallback if
// n_ev < 4; top-32 by score (ties -> lowest index, matching lax.top_k);
// valid events sorted ascending by time, invalid -> time 0, valid=false.
// ---------------------------------------------------------------------------
__global__ __launch_bounds__(256) void k_select(
    const float* __restrict__ z,
    int* __restrict__ ws_times, int* __restrict__ ws_valid,
    float* __restrict__ out_valid, float* __restrict__ out_times)
{
    __shared__ float s_sur[T_];
    __shared__ float red_v[4];
    __shared__ int   red_i[4];
    __shared__ int   s_cnt;
    __shared__ int   s_sel[E_];

    const int tid = threadIdx.x;
    const int b   = blockIdx.x;
    if (tid == 0) s_cnt = 0;
    __syncthreads();

    const float* zb = z + (size_t)b * T_ * 8;
    int cnt = 0;
    for (int t = tid; t < T_; t += 256) {
        const float* zp = zb + (size_t)t * 8;
        float4 z0 = *(const float4*)(zp);
        float4 z1 = *(const float4*)(zp + 4);
        float m = fmaxf(fmaxf(fmaxf(fabsf(z0.x), fabsf(z0.y)),
                              fmaxf(fabsf(z0.z), fabsf(z0.w))),
                        fmaxf(fmaxf(fabsf(z1.x), fabsf(z1.y)),
                              fmaxf(fabsf(z1.z), fabsf(z1.w))));
        s_sur[t] = m;
        if (m > 2.0f) cnt++;
    }
    atomicAdd(&s_cnt, cnt);
    __syncthreads();

    const int  n_ev = s_cnt;
    const bool fb   = (n_ev < 4);                 // top-k fallback
    const int  V    = fb ? E_ : (n_ev < E_ ? n_ev : E_);
    const int  lane = tid & 63;
    const int  wid  = tid >> 6;

    for (int k = 0; k < V; ++k) {
        float bv = -INFINITY;
        int   bi = 0x7fffffff;
        for (int t = tid; t < T_; t += 256) {
            float v = s_sur[t];
            if (!fb && !(v > 2.0f)) continue;     // not eligible unless fallback
            if (v > bv) { bv = v; bi = t; }       // strided ascending keeps lowest idx on tie
        }
        // wave butterfly-reduce (argmax, tie -> lower index)
        #pragma unroll
        for (int off = 32; off > 0; off >>= 1) {
            float ov = __shfl_down(bv, off);
            int   oi = __shfl_down(bi, off);
            if (ov > bv || (ov == bv && oi < bi)) { bv = ov; bi = oi; }
        }
        if (lane == 0) { red_v[wid] = bv; red_i[wid] = bi; }
        __syncthreads();
        if (tid == 0) {
            float best = red_v[0]; int besti = red_i[0];
            #pragma unroll
            for (int w = 1; w < 4; ++w) {
                if (red_v[w] > best || (red_v[w] == best && red_i[w] < besti)) {
                    best = red_v[w]; besti = red_i[w];
                }
            }
            s_sel[k] = besti;
            s_sur[besti] = -INFINITY;             // exclude from next pass
        }
        __syncthreads();
    }

    if (tid == 0) {
        // ascending insertion sort of the V selected times
        for (int i = 1; i < V; ++i) {
            int key = s_sel[i]; int j = i - 1;
            while (j >= 0 && s_sel[j] > key) { s_sel[j + 1] = s_sel[j]; --j; }
            s_sel[j + 1] = key;
        }
        for (int e = 0; e < E_; ++e) {
            int  valid = (e < V) ? 1 : 0;
            int  t     = valid ? s_sel[e] : 0;
            ws_times[b * E_ + e]  = t;
            ws_valid[b * E_ + e]  = valid;
            out_times[b * E_ + e] = (float)t;
            out_valid[b * E_ + e] = (float)valid;
        }
    }
}

// ---------------------------------------------------------------------------
// Kernel 2: fused gather + GEMM + epilogue.
// C[256 x 1024] = raw[256 x 1280] @ W^T, out += b_proj + time_embed[clip(t)]
// raw[row][f] = valid * (f < 1024 ? h_seq[b,t,f] : ent_flat[b,t,f-1024])
// Tiles: BM=64 rows, BN=64 cols, BK=32. 256 threads, 4x4 register block.
// ---------------------------------------------------------------------------
#define BM 64
#define BN 64
#define BK 32
#define PAD 4

__global__ __launch_bounds__(256) void k_gemm(
    const float* __restrict__ h_seq, const float* __restrict__ ent,
    const float* __restrict__ W, const float* __restrict__ bias,
    const float* __restrict__ temb,
    const int* __restrict__ ws_times, const int* __restrict__ ws_valid,
    float* __restrict__ out)
{
    __shared__ float As[BK][BM + PAD];   // As[f][row]  (transposed)
    __shared__ float Bs[BK][BN + PAD];   // Bs[f][col]  (transposed)

    const int tid  = threadIdx.x;
    const int row0 = blockIdx.x * BM;    // 0..3  -> rows
    const int col0 = blockIdx.y * BN;    // 0..15 -> cols

    // --- loader setup (each thread loads 2 float4 for A and 2 for B) ---
    size_t a_baseh[2], a_basee[2];
    float  a_v[2];
    int    a_row[2], a_f4[2];
    size_t b_base[2];
    int    b_d[2], b_f4[2];
    #pragma unroll
    for (int i = 0; i < 2; ++i) {
        int idx = tid + i * 256;          // 0..511
        int row = idx >> 3, f4 = idx & 7;
        a_row[i] = row; a_f4[i] = f4;
        int grow = row0 + row;            // global row = b*32 + e
        int t    = ws_times[grow];
        a_v[i]   = (float)ws_valid[grow];
        int bb   = grow >> 5;
        a_baseh[i] = ((size_t)bb * T_ + t) * D_   + f4 * 4;
        a_basee[i] = ((size_t)bb * T_ + t) * DENT + f4 * 4;
        int d = idx >> 3;
        b_d[i] = d; b_f4[i] = f4;
        b_base[i] = (size_t)(col0 + d) * F_ + f4 * 4;
    }

    const int rg = tid >> 4;   // 0..15 -> rows rg*4..rg*4+3
    const int cg = tid & 15;   // 0..15 -> cols cg*4..cg*4+3

    float acc[4][4] = {};

    for (int kc = 0; kc < F_ / BK; ++kc) {
        const int fbase = kc * BK;
        // load A tile (gathered, masked)
        #pragma unroll
        for (int i = 0; i < 2; ++i) {
            float4 val;
            if (fbase < D_) {
                val = *(const float4*)(h_seq + a_baseh[i] + fbase);
            } else {
                val = *(const float4*)(ent + a_basee[i] + (fbase - D_));
            }
            float v = a_v[i];
            int f = a_f4[i] * 4, r = a_row[i];
            As[f + 0][r] = val.x * v;
            As[f + 1][r] = val.y * v;
            As[f + 2][r] = val.z * v;
            As[f + 3][r] = val.w * v;
        }
        // load B tile (W rows are contiguous along f)
        #pragma unroll
        for (int i = 0; i < 2; ++i) {
            float4 wv = *(const float4*)(W + b_base[i] + fbase);
            int f = b_f4[i] * 4, d = b_d[i];
            Bs[f + 0][d] = wv.x;
            Bs[f + 1][d] = wv.y;
            Bs[f + 2][d] = wv.z;
            Bs[f + 3][d] = wv.w;
        }
        __syncthreads();
        #pragma unroll
        for (int ff = 0; ff < BK; ++ff) {
            const float4 av = *(const float4*)&As[ff][rg * 4];
            const float4 bv = *(const float4*)&Bs[ff][cg * 4];
            acc[0][0] = fmaf(av.x, bv.x, acc[0][0]);
            acc[0][1] = fmaf(av.x, bv.y, acc[0][1]);
            acc[0][2] = fmaf(av.x, bv.z, acc[0][2]);
            acc[0][3] = fmaf(av.x, bv.w, acc[0][3]);
            acc[1][0] = fmaf(av.y, bv.x, acc[1][0]);
            acc[1][1] = fmaf(av.y, bv.y, acc[1][1]);
            acc[1][2] = fmaf(av.y, bv.z, acc[1][2]);
            acc[1][3] = fmaf(av.y, bv.w, acc[1][3]);
            acc[2][0] = fmaf(av.z, bv.x, acc[2][0]);
            acc[2][1] = fmaf(av.z, bv.y, acc[2][1]);
            acc[2][2] = fmaf(av.z, bv.z, acc[2][2]);
            acc[2][3] = fmaf(av.z, bv.w, acc[2][3]);
            acc[3][0] = fmaf(av.w, bv.x, acc[3][0]);
            acc[3][1] = fmaf(av.w, bv.y, acc[3][1]);
            acc[3][2] = fmaf(av.w, bv.z, acc[3][2]);
            acc[3][3] = fmaf(av.w, bv.w, acc[3][3]);
        }
        __syncthreads();
    }

    // epilogue: + bias + time_embed[clip(t,0,511)], store float4
    const int cbase = col0 + cg * 4;
    const float4 bi = *(const float4*)(bias + cbase);
    #pragma unroll
    for (int j = 0; j < 4; ++j) {
        int grow = row0 + rg * 4 + j;
        int t    = ws_times[grow];
        int tc   = t < (TVOCAB - 1) ? t : (TVOCAB - 1);
        const float4 te = *(const float4*)(temb + (size_t)tc * D_ + cbase);
        float4 o;
        o.x = acc[j][0] + bi.x + te.x;
        o.y = acc[j][1] + bi.y + te.y;
        o.z = acc[j][2] + bi.z + te.z;
        o.w = acc[j][3] + bi.w + te.w;
        *(float4*)(out + (size_t)grow * D_ + cbase) = o;
    }
}

// ---------------------------------------------------------------------------
extern "C" void kernel_launch(void* const* d_in, const int* in_sizes, int n_in,
                              void* d_out, int out_size, void* d_ws, size_t ws_size,
                              hipStream_t stream)
{
    const float* h_seq = (const float*)d_in[0];
    const float* z     = (const float*)d_in[1];
    const float* ent   = (const float*)d_in[2];
    const float* W     = (const float*)d_in[3];
    const float* bias  = (const float*)d_in[4];
    const float* temb  = (const float*)d_in[5];

    float* out       = (float*)d_out;
    float* out_tape  = out;                       // B*E*D = 262144
    float* out_valid = out + (size_t)B_ * E_ * D_;        // 256
    float* out_times = out_valid + B_ * E_;               // 256

    int* ws_times = (int*)d_ws;          // 256 ints
    int* ws_valid = ws_times + B_ * E_;  // 256 ints

    k_select<<<B_, 256, 0, stream>>>(z, ws_times, ws_valid, out_valid, out_times);

    dim3 g2((B_ * E_) / BM, D_ / BN);    // 4 x 16
    k_gemm<<<g2, 256, 0, stream>>>(h_seq, ent, W, bias, temb,
                                   ws_times, ws_valid, out_tape);
}

// Round 2
// 87.787 us; speedup vs baseline: 1.8333x; 1.8333x over previous
//
#include <hip/hip_runtime.h>
#include <hip/hip_bf16.h>

// Problem constants (from reference setup_inputs)
#define B_   8
#define T_   4096
#define D_   1024
#define DENT 256
#define F_   1280          // D_ + DENT
#define E_   32            // MAX_EVENTS
#define TVOCAB 512
#define KS   4             // split-K slices
#define KCH  (F_ / KS)     // 320 = K elements per slice

// ---------------------------------------------------------------------------
// Kernel 1: event selection. One block per batch.
// surprise = max|z| over 8; mask = surprise > 2.0; fallback if n_ev < 4;
// top-32 by (value desc, index asc) — exact lax.top_k tie semantics via
// packed key (valueBits<<32)|~t; valid sorted ascending by time.
// Eligible candidates are compacted once so each argmax pass scans ~n_ev
// elements instead of T.
// ---------------------------------------------------------------------------
__global__ __launch_bounds__(256) void k_select(
    const float* __restrict__ z,
    int* __restrict__ ws_times, int* __restrict__ ws_valid,
    float* __restrict__ out_valid, float* __restrict__ out_times)
{
    __shared__ float s_sur[T_];
    __shared__ unsigned long long s_cand[T_];
    __shared__ int   s_ncand;
    __shared__ unsigned long long red_k[4];
    __shared__ int   red_p[4];
    __shared__ int   s_sel[E_];

    const int tid = threadIdx.x;
    const int b   = blockIdx.x;
    if (tid == 0) s_ncand = 0;
    __syncthreads();

    const float* zb = z + (size_t)b * T_ * 8;
    for (int t = tid; t < T_; t += 256) {
        const float* zp = zb + (size_t)t * 8;
        float4 z0 = *(const float4*)(zp);
        float4 z1 = *(const float4*)(zp + 4);
        float m = fmaxf(fmaxf(fmaxf(fabsf(z0.x), fabsf(z0.y)),
                              fmaxf(fabsf(z0.z), fabsf(z0.w))),
                        fmaxf(fmaxf(fabsf(z1.x), fabsf(z1.y)),
                              fmaxf(fabsf(z1.z), fabsf(z1.w))));
        s_sur[t] = m;
        if (m > 2.0f) {
            int pos = atomicAdd(&s_ncand, 1);
            s_cand[pos] = ((unsigned long long)__float_as_uint(m) << 32)
                        | (unsigned int)(0xFFFFFFFFu - (unsigned)t);
        }
    }
    __syncthreads();

    const int  n_ev  = s_ncand;
    const bool fb    = (n_ev < 4);
    const int  V     = fb ? E_ : (n_ev < E_ ? n_ev : E_);
    const int  nscan = fb ? T_ : n_ev;
    const int  lane  = tid & 63;
    const int  wid   = tid >> 6;

    for (int k = 0; k < V; ++k) {
        unsigned long long bk = 0ull;
        int bp = -1;
        for (int c = tid; c < nscan; c += 256) {
            unsigned long long kk;
            if (fb) {
                float v = s_sur[c];
                if (v < 0.0f) continue;            // removed sentinel
                kk = ((unsigned long long)__float_as_uint(v) << 32)
                   | (unsigned int)(0xFFFFFFFFu - (unsigned)c);
            } else {
                kk = s_cand[c];                    // 0 == removed
            }
            if (kk > bk) { bk = kk; bp = c; }
        }
        #pragma unroll
        for (int off = 32; off > 0; off >>= 1) {
            unsigned long long ok = __shfl_down(bk, off);
            int op = __shfl_down(bp, off);
            if (ok > bk) { bk = ok; bp = op; }
        }
        if (lane == 0) { red_k[wid] = bk; red_p[wid] = bp; }
        __syncthreads();
        if (tid == 0) {
            unsigned long long best = red_k[0]; int bestp = red_p[0];
            #pragma unroll
            for (int w = 1; w < 4; ++w)
                if (red_k[w] > best) { best = red_k[w]; bestp = red_p[w]; }
            s_sel[k] = (int)(0xFFFFFFFFu - (unsigned int)(best & 0xFFFFFFFFull));
            if (fb) s_sur[bestp] = -1.0f;
            else    s_cand[bestp] = 0ull;
        }
        __syncthreads();
    }

    if (tid == 0) {
        for (int i = 1; i < V; ++i) {              // ascending insertion sort
            int key = s_sel[i]; int j = i - 1;
            while (j >= 0 && s_sel[j] > key) { s_sel[j + 1] = s_sel[j]; --j; }
            s_sel[j + 1] = key;
        }
        for (int e = 0; e < E_; ++e) {
            int valid = (e < V) ? 1 : 0;
            int t     = valid ? s_sel[e] : 0;
            ws_times[b * E_ + e]  = t;
            ws_valid[b * E_ + e]  = valid;
            out_times[b * E_ + e] = (float)t;
            out_valid[b * E_ + e] = (float)valid;
        }
    }
}

// ---------------------------------------------------------------------------
// Kernel 2: split-K partial GEMM with gather.
// grid (4, 16, KS): 64x64 output tile, K-chunk of 320 (10 iters of BK=32).
// Register prefetch + LDS double buffer -> 1 barrier / K-iter.
// part[ks][row][col] = sum_{f in slice} raw[row][f] * W[col][f]
// ---------------------------------------------------------------------------
#define BM 64
#define BN 64
#define BK 32
#define PAD 4

__global__ __launch_bounds__(256) void k_gemm_part(
    const float* __restrict__ h_seq, const float* __restrict__ ent,
    const float* __restrict__ W,
    const int* __restrict__ ws_times, const int* __restrict__ ws_valid,
    float* __restrict__ part)
{
    __shared__ float As[2][BK][BM + PAD];
    __shared__ float Bs[2][BK][BN + PAD];

    const int tid  = threadIdx.x;
    const int row0 = blockIdx.x * BM;
    const int col0 = blockIdx.y * BN;
    const int ksl  = blockIdx.z;
    const int f0   = ksl * KCH;

    size_t a_baseh[2], a_basee[2], b_base[2];
    float  a_v[2];
    int    l_row[2], l_f4[2];
    #pragma unroll
    for (int i = 0; i < 2; ++i) {
        int idx = tid + i * 256;           // 0..511
        int row = idx >> 3, f4 = idx & 7;
        l_row[i] = row; l_f4[i] = f4;
        int grow = row0 + row;
        int t    = ws_times[grow];
        a_v[i]   = (float)ws_valid[grow];
        int bb   = grow >> 5;
        a_baseh[i] = ((size_t)bb * T_ + t) * D_   + f4 * 4;
        a_basee[i] = ((size_t)bb * T_ + t) * DENT + f4 * 4;
        b_base[i]  = (size_t)(col0 + row) * F_ + f4 * 4;
    }

    const int rg = tid >> 4;
    const int cg = tid & 15;

    float4 ra[2], rb[2];
    float acc[4][4] = {};

#define LOAD_TILE(KC) do {                                                   \
    int fbase = f0 + (KC) * BK;                                              \
    _Pragma("unroll")                                                        \
    for (int i = 0; i < 2; ++i) {                                            \
        if (fbase < D_) ra[i] = *(const float4*)(h_seq + a_baseh[i] + fbase);\
        else            ra[i] = *(const float4*)(ent + a_basee[i] + (fbase - D_)); \
        rb[i] = *(const float4*)(W + b_base[i] + fbase);                     \
    } } while (0)

#define STORE_TILE(BUF) do {                                                 \
    _Pragma("unroll")                                                        \
    for (int i = 0; i < 2; ++i) {                                            \
        int f = l_f4[i] * 4, r = l_row[i];                                   \
        float v = a_v[i];                                                    \
        As[BUF][f + 0][r] = ra[i].x * v;                                     \
        As[BUF][f + 1][r] = ra[i].y * v;                                     \
        As[BUF][f + 2][r] = ra[i].z * v;                                     \
        As[BUF][f + 3][r] = ra[i].w * v;                                     \
        Bs[BUF][f + 0][r] = rb[i].x;                                         \
        Bs[BUF][f + 1][r] = rb[i].y;                                         \
        Bs[BUF][f + 2][r] = rb[i].z;                                         \
        Bs[BUF][f + 3][r] = rb[i].w;                                         \
    } } while (0)

    LOAD_TILE(0);
    STORE_TILE(0);
    __syncthreads();

    const int NIT = KCH / BK;   // 10
    for (int kc = 0; kc < NIT; ++kc) {
        const int cur = kc & 1;
        if (kc < NIT - 1) LOAD_TILE(kc + 1);
        #pragma unroll
        for (int ff = 0; ff < BK; ++ff) {
            const float4 av = *(const float4*)&As[cur][ff][rg * 4];
            const float4 bv = *(const float4*)&Bs[cur][ff][cg * 4];
            acc[0][0] = fmaf(av.x, bv.x, acc[0][0]);
            acc[0][1] = fmaf(av.x, bv.y, acc[0][1]);
            acc[0][2] = fmaf(av.x, bv.z, acc[0][2]);
            acc[0][3] = fmaf(av.x, bv.w, acc[0][3]);
            acc[1][0] = fmaf(av.y, bv.x, acc[1][0]);
            acc[1][1] = fmaf(av.y, bv.y, acc[1][1]);
            acc[1][2] = fmaf(av.y, bv.z, acc[1][2]);
            acc[1][3] = fmaf(av.y, bv.w, acc[1][3]);
            acc[2][0] = fmaf(av.z, bv.x, acc[2][0]);
            acc[2][1] = fmaf(av.z, bv.y, acc[2][1]);
            acc[2][2] = fmaf(av.z, bv.z, acc[2][2]);
            acc[2][3] = fmaf(av.z, bv.w, acc[2][3]);
            acc[3][0] = fmaf(av.w, bv.x, acc[3][0]);
            acc[3][1] = fmaf(av.w, bv.y, acc[3][1]);
            acc[3][2] = fmaf(av.w, bv.z, acc[3][2]);
            acc[3][3] = fmaf(av.w, bv.w, acc[3][3]);
        }
        if (kc < NIT - 1) { STORE_TILE(cur ^ 1); __syncthreads(); }
    }
#undef LOAD_TILE
#undef STORE_TILE

    float* pout = part + (size_t)ksl * (B_ * E_ * D_);
    #pragma unroll
    for (int j = 0; j < 4; ++j) {
        int grow = row0 + rg * 4 + j;
        *(float4*)(pout + (size_t)grow * D_ + col0 + cg * 4) =
            make_float4(acc[j][0], acc[j][1], acc[j][2], acc[j][3]);
    }
}

// ---------------------------------------------------------------------------
// Kernel 3: reduce KS partials + bias + time_embed epilogue.
// One thread per float4 of the 256x1024 output.
// ---------------------------------------------------------------------------
__global__ __launch_bounds__(256) void k_reduce(
    const float* __restrict__ part, const float* __restrict__ bias,
    const float* __restrict__ temb, const int* __restrict__ ws_times,
    float* __restrict__ out)
{
    const int idx = blockIdx.x * 256 + threadIdx.x;   // float4 index, 65536 total
    const int row = idx >> 8;
    const int c   = (idx & 255) * 4;
    const size_t off = (size_t)row * D_ + c;
    const size_t stride = (size_t)B_ * E_ * D_;

    float4 s = *(const float4*)(part + off);
    #pragma unroll
    for (int k = 1; k < KS; ++k) {
        float4 p = *(const float4*)(part + k * stride + off);
        s.x += p.x; s.y += p.y; s.z += p.z; s.w += p.w;
    }
    const float4 bi = *(const float4*)(bias + c);
    int t  = ws_times[row];
    int tc = t < (TVOCAB - 1) ? t : (TVOCAB - 1);
    const float4 te = *(const float4*)(temb + (size_t)tc * D_ + c);
    s.x += bi.x + te.x; s.y += bi.y + te.y;
    s.z += bi.z + te.z; s.w += bi.w + te.w;
    *(float4*)(out + off) = s;
}

// ---------------------------------------------------------------------------
// Fallback single-kernel GEMM (if ws too small for partials) — round-1 code.
// ---------------------------------------------------------------------------
__global__ __launch_bounds__(256) void k_gemm_full(
    const float* __restrict__ h_seq, const float* __restrict__ ent,
    const float* __restrict__ W, const float* __restrict__ bias,
    const float* __restrict__ temb,
    const int* __restrict__ ws_times, const int* __restrict__ ws_valid,
    float* __restrict__ out)
{
    __shared__ float As[BK][BM + PAD];
    __shared__ float Bs[BK][BN + PAD];

    const int tid  = threadIdx.x;
    const int row0 = blockIdx.x * BM;
    const int col0 = blockIdx.y * BN;

    size_t a_baseh[2], a_basee[2], b_base[2];
    float  a_v[2];
    int    l_row[2], l_f4[2];
    #pragma unroll
    for (int i = 0; i < 2; ++i) {
        int idx = tid + i * 256;
        int row = idx >> 3, f4 = idx & 7;
        l_row[i] = row; l_f4[i] = f4;
        int grow = row0 + row;
        int t    = ws_times[grow];
        a_v[i]   = (float)ws_valid[grow];
        int bb   = grow >> 5;
        a_baseh[i] = ((size_t)bb * T_ + t) * D_   + f4 * 4;
        a_basee[i] = ((size_t)bb * T_ + t) * DENT + f4 * 4;
        b_base[i]  = (size_t)(col0 + row) * F_ + f4 * 4;
    }

    const int rg = tid >> 4;
    const int cg = tid & 15;
    float acc[4][4] = {};

    for (int kc = 0; kc < F_ / BK; ++kc) {
        const int fbase = kc * BK;
        #pragma unroll
        for (int i = 0; i < 2; ++i) {
            float4 val;
            if (fbase < D_) val = *(const float4*)(h_seq + a_baseh[i] + fbase);
            else            val = *(const float4*)(ent + a_basee[i] + (fbase - D_));
            float v = a_v[i];
            int f = l_f4[i] * 4, r = l_row[i];
            As[f + 0][r] = val.x * v;
            As[f + 1][r] = val.y * v;
            As[f + 2][r] = val.z * v;
            As[f + 3][r] = val.w * v;
            float4 wv = *(const float4*)(W + b_base[i] + fbase);
            Bs[f + 0][r] = wv.x;
            Bs[f + 1][r] = wv.y;
            Bs[f + 2][r] = wv.z;
            Bs[f + 3][r] = wv.w;
        }
        __syncthreads();
        #pragma unroll
        for (int ff = 0; ff < BK; ++ff) {
            const float4 av = *(const float4*)&As[ff][rg * 4];
            const float4 bv = *(const float4*)&Bs[ff][cg * 4];
            #pragma unroll
            for (int j = 0; j < 4; ++j) {
                float a = (&av.x)[j];
                acc[j][0] = fmaf(a, bv.x, acc[j][0]);
                acc[j][1] = fmaf(a, bv.y, acc[j][1]);
                acc[j][2] = fmaf(a, bv.z, acc[j][2]);
                acc[j][3] = fmaf(a, bv.w, acc[j][3]);
            }
        }
        __syncthreads();
    }

    const int cbase = col0 + cg * 4;
    const float4 bi = *(const float4*)(bias + cbase);
    #pragma unroll
    for (int j = 0; j < 4; ++j) {
        int grow = row0 + rg * 4 + j;
        int t    = ws_times[grow];
        int tc   = t < (TVOCAB - 1) ? t : (TVOCAB - 1);
        const float4 te = *(const float4*)(temb + (size_t)tc * D_ + cbase);
        float4 o;
        o.x = acc[j][0] + bi.x + te.x;
        o.y = acc[j][1] + bi.y + te.y;
        o.z = acc[j][2] + bi.z + te.z;
        o.w = acc[j][3] + bi.w + te.w;
        *(float4*)(out + (size_t)grow * D_ + cbase) = o;
    }
}

// ---------------------------------------------------------------------------
extern "C" void kernel_launch(void* const* d_in, const int* in_sizes, int n_in,
                              void* d_out, int out_size, void* d_ws, size_t ws_size,
                              hipStream_t stream)
{
    const float* h_seq = (const float*)d_in[0];
    const float* z     = (const float*)d_in[1];
    const float* ent   = (const float*)d_in[2];
    const float* W     = (const float*)d_in[3];
    const float* bias  = (const float*)d_in[4];
    const float* temb  = (const float*)d_in[5];

    float* out       = (float*)d_out;
    float* out_tape  = out;                                // B*E*D = 262144
    float* out_valid = out + (size_t)B_ * E_ * D_;         // 256
    float* out_times = out_valid + B_ * E_;                // 256

    int* ws_times = (int*)d_ws;           // 256 ints
    int* ws_valid = ws_times + B_ * E_;   // 256 ints
    float* part   = (float*)((char*)d_ws + 2048);          // KS*256*1024 floats

    k_select<<<B_, 256, 0, stream>>>(z, ws_times, ws_valid, out_valid, out_times);

    const size_t need = 2048 + (size_t)KS * B_ * E_ * D_ * sizeof(float);
    if (ws_size >= need) {
        dim3 g2((B_ * E_) / BM, D_ / BN, KS);   // 4 x 16 x 4 = 256 blocks
        k_gemm_part<<<g2, 256, 0, stream>>>(h_seq, ent, W, ws_times, ws_valid, part);
        k_reduce<<<(B_ * E_ * D_ / 4) / 256, 256, 0, stream>>>(
            part, bias, temb, ws_times, out_tape);
    } else {
        dim3 g2((B_ * E_) / BM, D_ / BN);       // 4 x 16
        k_gemm_full<<<g2, 256, 0, stream>>>(h_seq, ent, W, bias, temb,
                                            ws_times, ws_valid, out_tape);
    }
}

// Round 3
// 82.081 us; speedup vs baseline: 1.9608x; 1.0695x over previous
//
#include <hip/hip_runtime.h>
#include <hip/hip_bf16.h>

// Problem constants (from reference setup_inputs)
#define B_   8
#define T_   4096
#define D_   1024
#define DENT 256
#define F_   1280          // D_ + DENT
#define E_   32            // MAX_EVENTS
#define TVOCAB 512
#define KS   4             // split-K slices
#define KCH  (F_ / KS)     // 320

// ---------------------------------------------------------------------------
// Kernel 1: event selection via 4-pass radix-select. One block per batch.
// surprise = max|z| over 8; mask = surprise > 2.0; fallback if n_ev < 4;
// top-32 by (value desc, index asc) = exact lax.top_k; output sorted by time.
// Also zeroes the split-K completion counters (block 0).
// ---------------------------------------------------------------------------
__global__ __launch_bounds__(256) void k_select(
    const float* __restrict__ z,
    int* __restrict__ ws_times, int* __restrict__ ws_valid,
    int* __restrict__ ws_cnt,
    float* __restrict__ out_valid, float* __restrict__ out_times)
{
    __shared__ float    s_sur[T_];          // 16 KB
    __shared__ unsigned s_bins[256];
    __shared__ int s_cnt, s_nsel, s_ntie;
    __shared__ int s_bbin;
    __shared__ unsigned s_bcg;
    __shared__ int s_selt[E_];
    __shared__ int s_tiet[256];
    __shared__ int s_sorted[E_];

    const int tid = threadIdx.x;
    const int b   = blockIdx.x;

    if (b == 0 && tid < 64) ws_cnt[tid] = 0;     // split-K counters (gemm runs after)
    if (tid == 0) { s_cnt = 0; s_nsel = 0; s_ntie = 0; }
    __syncthreads();

    // ---- surprise = max |z| over 8 dims ----
    const float* zb = z + (size_t)b * T_ * 8;
    int cnt = 0;
    for (int t = tid; t < T_; t += 256) {
        const float* zp = zb + (size_t)t * 8;
        float4 z0 = *(const float4*)(zp);
        float4 z1 = *(const float4*)(zp + 4);
        float m = fmaxf(fmaxf(fmaxf(fabsf(z0.x), fabsf(z0.y)),
                              fmaxf(fabsf(z0.z), fabsf(z0.w))),
                        fmaxf(fmaxf(fabsf(z1.x), fabsf(z1.y)),
                              fmaxf(fabsf(z1.z), fabsf(z1.w))));
        s_sur[t] = m;
        if (m > 2.0f) cnt++;
    }
    atomicAdd(&s_cnt, cnt);
    __syncthreads();

    const int  n_ev = s_cnt;
    const bool fb   = (n_ev < 4);
    const int  V    = fb ? E_ : (n_ev < E_ ? n_ev : E_);

    if (!fb && n_ev <= E_) {
        // all eligible are selected — just collect
        for (int t = tid; t < T_; t += 256)
            if (s_sur[t] > 2.0f) { int p = atomicAdd(&s_nsel, 1); s_selt[p] = t; }
        __syncthreads();
    } else {
        // ---- radix-select the 32nd largest value (positive floats: uint-monotone) ----
        unsigned prefix = 0;
        int need = E_;
        for (int p = 0; p < 4; ++p) {
            const int shift = 24 - 8 * p;
            s_bins[tid] = 0;
            __syncthreads();
            for (int t = tid; t < T_; t += 256) {
                float v = s_sur[t];
                if (!fb && !(v > 2.0f)) continue;
                unsigned key = __float_as_uint(v);
                bool match = (p == 0) || ((key >> (shift + 8)) == prefix);
                if (match) atomicAdd(&s_bins[(key >> shift) & 255u], 1u);
            }
            __syncthreads();
            if (tid < 64) {
                unsigned b0 = s_bins[4*tid+0], b1 = s_bins[4*tid+1];
                unsigned b2 = s_bins[4*tid+2], b3 = s_bins[4*tid+3];
                unsigned lsum = b0 + b1 + b2 + b3;
                unsigned suf = lsum;                       // inclusive suffix over lanes
                #pragma unroll
                for (int off = 1; off < 64; off <<= 1) {
                    unsigned o = __shfl_down(suf, off);
                    if (tid + off < 64) suf += o;
                }
                unsigned excl = suf - lsum;                // sum of lanes above
                unsigned cg3 = excl;
                unsigned cg2 = cg3 + b3;
                unsigned cg1 = cg2 + b2;
                unsigned cg0 = cg1 + b1;
                unsigned un  = (unsigned)need;
                if (cg3 < un && cg3 + b3 >= un) { s_bbin = 4*tid+3; s_bcg = cg3; }
                if (cg2 < un && cg2 + b2 >= un) { s_bbin = 4*tid+2; s_bcg = cg2; }
                if (cg1 < un && cg1 + b1 >= un) { s_bbin = 4*tid+1; s_bcg = cg1; }
                if (cg0 < un && cg0 + b0 >= un) { s_bbin = 4*tid+0; s_bcg = cg0; }
            }
            __syncthreads();
            need  -= (int)s_bcg;
            prefix = (prefix << 8) | (unsigned)s_bbin;
        }
        const unsigned vstar = prefix;   // exact 32nd-largest value bits
        const int need_eq = need;        // how many pivot-equal elems to take (smallest idx)

        for (int t = tid; t < T_; t += 256) {
            float v = s_sur[t];
            if (!fb && !(v > 2.0f)) continue;
            unsigned key = __float_as_uint(v);
            if (key > vstar)       { int p = atomicAdd(&s_nsel, 1); s_selt[p] = t; }
            else if (key == vstar) { int p = atomicAdd(&s_ntie, 1); if (p < 256) s_tiet[p] = t; }
        }
        __syncthreads();
        const int ntie = s_ntie > 256 ? 256 : s_ntie;
        for (int q = 0; q < need_eq; ++q) {        // usually 1 iteration
            if (tid < 64) {
                int best = 0x7fffffff, bpos = -1;
                for (int c = tid; c < ntie; c += 64) {
                    int tt = s_tiet[c];
                    if (tt < best) { best = tt; bpos = c; }
                }
                #pragma unroll
                for (int off = 32; off > 0; off >>= 1) {
                    int ov = __shfl_down(best, off);
                    int op = __shfl_down(bpos, off);
                    if (ov < best) { best = ov; bpos = op; }
                }
                if (tid == 0) { s_selt[s_nsel + q] = best; s_tiet[bpos] = 0x7fffffff; }
            }
            __syncthreads();
        }
    }

    // ---- rank-sort the V selected (distinct) times ascending ----
    if (tid < V) {
        int ti = s_selt[tid];
        int rank = 0;
        for (int j = 0; j < V; ++j) rank += (s_selt[j] < ti);
        s_sorted[rank] = ti;
    }
    __syncthreads();
    if (tid < E_) {
        int valid = (tid < V) ? 1 : 0;
        int t     = valid ? s_sorted[tid] : 0;
        ws_times[b * E_ + tid]  = t;
        ws_valid[b * E_ + tid]  = valid;
        out_times[b * E_ + tid] = (float)t;
        out_valid[b * E_ + tid] = (float)valid;
    }
}

// ---------------------------------------------------------------------------
// Kernel 2: split-K GEMM with gather + in-kernel deterministic reduction.
// 256 blocks (1-D, XCD-swizzled): tile = 64x64, K-chunk 320 (10 x BK=32).
// Each block writes its partial; the last block per tile (completion counter)
// sums the KS partials in fixed k order + bias + time_embed -> out.
// ---------------------------------------------------------------------------
#define BM 64
#define BN 64
#define BK 32
#define PAD 4

__global__ __launch_bounds__(256) void k_gemm_fused(
    const float* __restrict__ h_seq, const float* __restrict__ ent,
    const float* __restrict__ W, const float* __restrict__ bias,
    const float* __restrict__ temb,
    const int* __restrict__ ws_times, const int* __restrict__ ws_valid,
    int* __restrict__ ws_cnt, float* __restrict__ part,
    float* __restrict__ out)
{
    __shared__ float As[2][BK][BM + PAD];
    __shared__ float Bs[2][BK][BN + PAD];
    __shared__ int s_old;

    const int tid = threadIdx.x;
    // XCD-aware swizzle: co-locate the 4 row-tile blocks sharing one W panel.
    const int flat  = blockIdx.x;          // 0..255
    const int xcd   = flat & 7;
    const int idx   = flat >> 3;           // 0..31
    const int combo = xcd * 8 + (idx >> 2);// 0..63 -> (col-tile, k-slice)
    const int xr    = idx & 3;             // row tile 0..3
    const int yc    = combo & 15;          // col tile 0..15
    const int zs    = combo >> 4;          // k-slice 0..3

    const int row0 = xr * BM;
    const int col0 = yc * BN;
    const int f0   = zs * KCH;
    const int tile = xr * 16 + yc;

    size_t a_baseh[2], a_basee[2], b_base[2];
    float  a_v[2];
    int    l_row[2], l_f4[2];
    #pragma unroll
    for (int i = 0; i < 2; ++i) {
        int idx2 = tid + i * 256;          // 0..511
        int row = idx2 >> 3, f4 = idx2 & 7;
        l_row[i] = row; l_f4[i] = f4;
        int grow = row0 + row;
        int t    = ws_times[grow];
        a_v[i]   = (float)ws_valid[grow];
        int bb   = grow >> 5;
        a_baseh[i] = ((size_t)bb * T_ + t) * D_   + f4 * 4;
        a_basee[i] = ((size_t)bb * T_ + t) * DENT + f4 * 4;
        b_base[i]  = (size_t)(col0 + row) * F_ + f4 * 4;
    }

    const int rg = tid >> 4;
    const int cg = tid & 15;

    float4 ra[2], rb[2];
    float acc[4][4] = {};

#define LOAD_TILE(KC) do {                                                   \
    int fbase = f0 + (KC) * BK;                                              \
    _Pragma("unroll")                                                        \
    for (int i = 0; i < 2; ++i) {                                            \
        if (fbase < D_) ra[i] = *(const float4*)(h_seq + a_baseh[i] + fbase);\
        else            ra[i] = *(const float4*)(ent + a_basee[i] + (fbase - D_)); \
        rb[i] = *(const float4*)(W + b_base[i] + fbase);                     \
    } } while (0)

#define STORE_TILE(BUF) do {                                                 \
    _Pragma("unroll")                                                        \
    for (int i = 0; i < 2; ++i) {                                            \
        int f = l_f4[i] * 4, r = l_row[i];                                   \
        float v = a_v[i];                                                    \
        As[BUF][f + 0][r] = ra[i].x * v;                                     \
        As[BUF][f + 1][r] = ra[i].y * v;                                     \
        As[BUF][f + 2][r] = ra[i].z * v;                                     \
        As[BUF][f + 3][r] = ra[i].w * v;                                     \
        Bs[BUF][f + 0][r] = rb[i].x;                                         \
        Bs[BUF][f + 1][r] = rb[i].y;                                         \
        Bs[BUF][f + 2][r] = rb[i].z;                                         \
        Bs[BUF][f + 3][r] = rb[i].w;                                         \
    } } while (0)

    LOAD_TILE(0);
    STORE_TILE(0);
    __syncthreads();

    const int NIT = KCH / BK;   // 10
    for (int kc = 0; kc < NIT; ++kc) {
        const int cur = kc & 1;
        if (kc < NIT - 1) LOAD_TILE(kc + 1);
        #pragma unroll
        for (int ff = 0; ff < BK; ++ff) {
            const float4 av = *(const float4*)&As[cur][ff][rg * 4];
            const float4 bv = *(const float4*)&Bs[cur][ff][cg * 4];
            acc[0][0] = fmaf(av.x, bv.x, acc[0][0]);
            acc[0][1] = fmaf(av.x, bv.y, acc[0][1]);
            acc[0][2] = fmaf(av.x, bv.z, acc[0][2]);
            acc[0][3] = fmaf(av.x, bv.w, acc[0][3]);
            acc[1][0] = fmaf(av.y, bv.x, acc[1][0]);
            acc[1][1] = fmaf(av.y, bv.y, acc[1][1]);
            acc[1][2] = fmaf(av.y, bv.z, acc[1][2]);
            acc[1][3] = fmaf(av.y, bv.w, acc[1][3]);
            acc[2][0] = fmaf(av.z, bv.x, acc[2][0]);
            acc[2][1] = fmaf(av.z, bv.y, acc[2][1]);
            acc[2][2] = fmaf(av.z, bv.z, acc[2][2]);
            acc[2][3] = fmaf(av.z, bv.w, acc[2][3]);
            acc[3][0] = fmaf(av.w, bv.x, acc[3][0]);
            acc[3][1] = fmaf(av.w, bv.y, acc[3][1]);
            acc[3][2] = fmaf(av.w, bv.z, acc[3][2]);
            acc[3][3] = fmaf(av.w, bv.w, acc[3][3]);
        }
        if (kc < NIT - 1) { STORE_TILE(cur ^ 1); __syncthreads(); }
    }
#undef LOAD_TILE
#undef STORE_TILE

    // ---- write partial slice ----
    float* pout = part + (size_t)zs * (B_ * E_ * D_);
    #pragma unroll
    for (int j = 0; j < 4; ++j) {
        int grow = row0 + rg * 4 + j;
        *(float4*)(pout + (size_t)grow * D_ + col0 + cg * 4) =
            make_float4(acc[j][0], acc[j][1], acc[j][2], acc[j][3]);
    }

    // ---- completion counter; last block per tile reduces ----
    __threadfence();
    __syncthreads();
    if (tid == 0) s_old = atomicAdd(&ws_cnt[tile], 1);
    __syncthreads();
    if (s_old == KS - 1) {
        __threadfence();
        const int cbase = col0 + cg * 4;
        const float4 bi = *(const float4*)(bias + cbase);
        #pragma unroll
        for (int j = 0; j < 4; ++j) {
            int grow = row0 + rg * 4 + j;
            float4 s = make_float4(0.f, 0.f, 0.f, 0.f);
            #pragma unroll
            for (int k = 0; k < KS; ++k) {   // fixed order -> deterministic
                const float4 pv = *(const float4*)(part
                    + (size_t)k * (B_ * E_ * D_) + (size_t)grow * D_ + cbase);
                s.x += pv.x; s.y += pv.y; s.z += pv.z; s.w += pv.w;
            }
            int t  = ws_times[grow];
            int tc = t < (TVOCAB - 1) ? t : (TVOCAB - 1);
            const float4 te = *(const float4*)(temb + (size_t)tc * D_ + cbase);
            s.x += bi.x + te.x; s.y += bi.y + te.y;
            s.z += bi.z + te.z; s.w += bi.w + te.w;
            *(float4*)(out + (size_t)grow * D_ + cbase) = s;
        }
    }
}

// ---------------------------------------------------------------------------
// Fallback single-kernel GEMM (if ws too small) — known-good round-1 code.
// ---------------------------------------------------------------------------
__global__ __launch_bounds__(256) void k_gemm_full(
    const float* __restrict__ h_seq, const float* __restrict__ ent,
    const float* __restrict__ W, const float* __restrict__ bias,
    const float* __restrict__ temb,
    const int* __restrict__ ws_times, const int* __restrict__ ws_valid,
    float* __restrict__ out)
{
    __shared__ float As[BK][BM + PAD];
    __shared__ float Bs[BK][BN + PAD];

    const int tid  = threadIdx.x;
    const int row0 = blockIdx.x * BM;
    const int col0 = blockIdx.y * BN;

    size_t a_baseh[2], a_basee[2], b_base[2];
    float  a_v[2];
    int    l_row[2], l_f4[2];
    #pragma unroll
    for (int i = 0; i < 2; ++i) {
        int idx = tid + i * 256;
        int row = idx >> 3, f4 = idx & 7;
        l_row[i] = row; l_f4[i] = f4;
        int grow = row0 + row;
        int t    = ws_times[grow];
        a_v[i]   = (float)ws_valid[grow];
        int bb   = grow >> 5;
        a_baseh[i] = ((size_t)bb * T_ + t) * D_   + f4 * 4;
        a_basee[i] = ((size_t)bb * T_ + t) * DENT + f4 * 4;
        b_base[i]  = (size_t)(col0 + row) * F_ + f4 * 4;
    }

    const int rg = tid >> 4;
    const int cg = tid & 15;
    float acc[4][4] = {};

    for (int kc = 0; kc < F_ / BK; ++kc) {
        const int fbase = kc * BK;
        #pragma unroll
        for (int i = 0; i < 2; ++i) {
            float4 val;
            if (fbase < D_) val = *(const float4*)(h_seq + a_baseh[i] + fbase);
            else            val = *(const float4*)(ent + a_basee[i] + (fbase - D_));
            float v = a_v[i];
            int f = l_f4[i] * 4, r = l_row[i];
            As[f + 0][r] = val.x * v;
            As[f + 1][r] = val.y * v;
            As[f + 2][r] = val.z * v;
            As[f + 3][r] = val.w * v;
            float4 wv = *(const float4*)(W + b_base[i] + fbase);
            Bs[f + 0][r] = wv.x;
            Bs[f + 1][r] = wv.y;
            Bs[f + 2][r] = wv.z;
            Bs[f + 3][r] = wv.w;
        }
        __syncthreads();
        #pragma unroll
        for (int ff = 0; ff < BK; ++ff) {
            const float4 av = *(const float4*)&As[ff][rg * 4];
            const float4 bv = *(const float4*)&Bs[ff][cg * 4];
            #pragma unroll
            for (int j = 0; j < 4; ++j) {
                float a = (&av.x)[j];
                acc[j][0] = fmaf(a, bv.x, acc[j][0]);
                acc[j][1] = fmaf(a, bv.y, acc[j][1]);
                acc[j][2] = fmaf(a, bv.z, acc[j][2]);
                acc[j][3] = fmaf(a, bv.w, acc[j][3]);
            }
        }
        __syncthreads();
    }

    const int cbase = col0 + cg * 4;
    const float4 bi = *(const float4*)(bias + cbase);
    #pragma unroll
    for (int j = 0; j < 4; ++j) {
        int grow = row0 + rg * 4 + j;
        int t    = ws_times[grow];
        int tc   = t < (TVOCAB - 1) ? t : (TVOCAB - 1);
        const float4 te = *(const float4*)(temb + (size_t)tc * D_ + cbase);
        float4 o;
        o.x = acc[j][0] + bi.x + te.x;
        o.y = acc[j][1] + bi.y + te.y;
        o.z = acc[j][2] + bi.z + te.z;
        o.w = acc[j][3] + bi.w + te.w;
        *(float4*)(out + (size_t)grow * D_ + cbase) = o;
    }
}

// ---------------------------------------------------------------------------
extern "C" void kernel_launch(void* const* d_in, const int* in_sizes, int n_in,
                              void* d_out, int out_size, void* d_ws, size_t ws_size,
                              hipStream_t stream)
{
    const float* h_seq = (const float*)d_in[0];
    const float* z     = (const float*)d_in[1];
    const float* ent   = (const float*)d_in[2];
    const float* W     = (const float*)d_in[3];
    const float* bias  = (const float*)d_in[4];
    const float* temb  = (const float*)d_in[5];

    float* out       = (float*)d_out;
    float* out_tape  = out;                                // 262144
    float* out_valid = out + (size_t)B_ * E_ * D_;         // 256
    float* out_times = out_valid + B_ * E_;                // 256

    // ws layout: [0]  times (256 int) | [1KB] valid (256 int)
    //            [2KB] split-K counters (64 int) | [4KB] partials (4 MB)
    int*   ws_times = (int*)d_ws;
    int*   ws_valid = (int*)((char*)d_ws + 1024);
    int*   ws_cnt   = (int*)((char*)d_ws + 2048);
    float* part     = (float*)((char*)d_ws + 4096);

    k_select<<<B_, 256, 0, stream>>>(z, ws_times, ws_valid, ws_cnt,
                                     out_valid, out_times);

    const size_t need = 4096 + (size_t)KS * B_ * E_ * D_ * sizeof(float);
    if (ws_size >= need) {
        k_gemm_fused<<<256, 256, 0, stream>>>(h_seq, ent, W, bias, temb,
                                              ws_times, ws_valid, ws_cnt,
                                              part, out_tape);
    } else {
        dim3 g2((B_ * E_) / BM, D_ / BN);
        k_gemm_full<<<g2, 256, 0, stream>>>(h_seq, ent, W, bias, temb,
                                            ws_times, ws_valid, out_tape);
    }
}

// Round 4
// 75.787 us; speedup vs baseline: 2.1236x; 1.0830x over previous
//
#include <hip/hip_runtime.h>
#include <hip/hip_bf16.h>

// Problem constants (from reference setup_inputs)
#define B_   8
#define T_   4096
#define D_   1024
#define DENT 256
#define F_   1280          // D_ + DENT
#define E_   32            // MAX_EVENTS
#define TVOCAB 512
#define KS   4             // split-K slices
#define KCH  (F_ / KS)     // 320
#define THRB 0x40000000u   // __float_as_uint(2.0f); m>=0 so bit-compare == float-compare

// ---------------------------------------------------------------------------
// Kernel 1: event selection. One block per batch, 1024 threads.
// Keys (surprise bit patterns) live in registers (4 per thread).
// Radix-select (4x8-bit, per-wave private histograms -> no cross-wave LDS
// atomic contention) finds the exact 32nd-largest; ties resolved smallest-
// index-first (exact lax.top_k semantics). Output sorted ascending by time.
// ---------------------------------------------------------------------------
__global__ __launch_bounds__(1024) void k_select(
    const float* __restrict__ z,
    int* __restrict__ ws_times, int* __restrict__ ws_valid,
    int* __restrict__ ws_cnt,
    float* __restrict__ out_valid, float* __restrict__ out_times)
{
    __shared__ unsigned s_hist[16 * 257];   // per-wave histograms, stride 257
    __shared__ unsigned s_tot[256];
    __shared__ int s_cnt, s_nsel;
    __shared__ int s_bbin; __shared__ unsigned s_bcg;
    __shared__ int s_selt[E_], s_sorted[E_];
    __shared__ int s_red[16];
    __shared__ int s_prev;

    const int tid  = threadIdx.x;
    const int b    = blockIdx.x;
    const int lane = tid & 63;
    const int wid  = tid >> 6;

    if (b == 0 && tid < 64) ws_cnt[tid] = 0;   // split-K counters for gemm
    if (tid == 0) { s_cnt = 0; s_nsel = 0; }
    __syncthreads();

    // ---- surprise keys into registers (thread owns t = tid + j*1024) ----
    unsigned key[4];
    int cnt = 0;
    const float* zb = z + (size_t)b * T_ * 8;
    #pragma unroll
    for (int j = 0; j < 4; ++j) {
        const int t = tid + j * 1024;
        const float* zp = zb + (size_t)t * 8;
        float4 z0 = *(const float4*)(zp);
        float4 z1 = *(const float4*)(zp + 4);
        float m = fmaxf(fmaxf(fmaxf(fabsf(z0.x), fabsf(z0.y)),
                              fmaxf(fabsf(z0.z), fabsf(z0.w))),
                        fmaxf(fmaxf(fabsf(z1.x), fabsf(z1.y)),
                              fmaxf(fabsf(z1.z), fabsf(z1.w))));
        key[j] = __float_as_uint(m);
        if (key[j] > THRB) cnt++;
    }
    // wave-reduce eligible count, one atomic per wave
    #pragma unroll
    for (int off = 32; off > 0; off >>= 1) cnt += __shfl_down(cnt, off);
    if (lane == 0) atomicAdd(&s_cnt, cnt);
    __syncthreads();

    const int  n_ev = s_cnt;
    const bool fb   = (n_ev < 4);
    const int  V    = fb ? E_ : (n_ev < E_ ? n_ev : E_);

    if (!fb && n_ev <= E_) {
        // all eligible selected — direct collection
        #pragma unroll
        for (int j = 0; j < 4; ++j)
            if (key[j] > THRB) { int p = atomicAdd(&s_nsel, 1); s_selt[p] = tid + j * 1024; }
        __syncthreads();
    } else {
        // ---- radix-select the 32nd-largest key among eligible ----
        unsigned prefix = 0;
        int need = E_;
        for (int p = 0; p < 4; ++p) {
            const int shift = 24 - 8 * p;
            for (int i = tid; i < 16 * 257; i += 1024) s_hist[i] = 0;
            __syncthreads();
            unsigned* h = s_hist + wid * 257;
            #pragma unroll
            for (int j = 0; j < 4; ++j) {
                bool elig = fb || (key[j] > THRB);
                if (elig && (p == 0 || (key[j] >> (shift + 8)) == prefix))
                    atomicAdd(&h[(key[j] >> shift) & 255u], 1u);
            }
            __syncthreads();
            if (tid < 256) {
                unsigned s = 0;
                #pragma unroll
                for (int w = 0; w < 16; ++w) s += s_hist[w * 257 + tid];
                s_tot[tid] = s;
            }
            __syncthreads();
            if (tid < 64) {
                unsigned b0 = s_tot[4*tid+0], b1 = s_tot[4*tid+1];
                unsigned b2 = s_tot[4*tid+2], b3 = s_tot[4*tid+3];
                unsigned lsum = b0 + b1 + b2 + b3;
                unsigned suf = lsum;                   // inclusive suffix over lanes
                #pragma unroll
                for (int off = 1; off < 64; off <<= 1) {
                    unsigned o = __shfl_down(suf, off);
                    if (tid + off < 64) suf += o;
                }
                unsigned excl = suf - lsum;            // sum of lanes above
                unsigned cg3 = excl;
                unsigned cg2 = cg3 + b3;
                unsigned cg1 = cg2 + b2;
                unsigned cg0 = cg1 + b1;
                unsigned un  = (unsigned)need;
                if (cg3 < un && cg3 + b3 >= un) { s_bbin = 4*tid+3; s_bcg = cg3; }
                if (cg2 < un && cg2 + b2 >= un) { s_bbin = 4*tid+2; s_bcg = cg2; }
                if (cg1 < un && cg1 + b1 >= un) { s_bbin = 4*tid+1; s_bcg = cg1; }
                if (cg0 < un && cg0 + b0 >= un) { s_bbin = 4*tid+0; s_bcg = cg0; }
            }
            __syncthreads();
            need  -= (int)s_bcg;
            prefix = (prefix << 8) | (unsigned)s_bbin;
            __syncthreads();
        }
        const unsigned vstar   = prefix;   // exact 32nd-largest value bits
        const int      need_eq = need;     // pivot-equal slots (smallest index first)

        // collect strictly-greater
        #pragma unroll
        for (int j = 0; j < 4; ++j) {
            bool elig = fb || (key[j] > THRB);
            if (elig && key[j] > vstar) { int p = atomicAdd(&s_nsel, 1); s_selt[p] = tid + j * 1024; }
        }
        __syncthreads();
        // pivot-equal ties: take need_eq smallest indices, via register re-scan
        int prev = -1;
        const int base = s_nsel;
        for (int q = 0; q < need_eq; ++q) {
            int best = 0x7fffffff;
            #pragma unroll
            for (int j = 0; j < 4; ++j) {
                bool elig = fb || (key[j] > THRB);
                int  t    = tid + j * 1024;
                if (elig && key[j] == vstar && t > prev && t < best) best = t;
            }
            #pragma unroll
            for (int off = 32; off > 0; off >>= 1) {
                int o = __shfl_down(best, off);
                if (o < best) best = o;
            }
            if (lane == 0) s_red[wid] = best;
            __syncthreads();
            if (tid == 0) {
                int m = s_red[0];
                #pragma unroll
                for (int w = 1; w < 16; ++w) if (s_red[w] < m) m = s_red[w];
                s_selt[base + q] = m;
                s_prev = m;
            }
            __syncthreads();
            prev = s_prev;
        }
    }

    // ---- rank-sort the V selected (distinct) times ascending ----
    if (tid < V) {
        int ti = s_selt[tid];
        int rank = 0;
        for (int j = 0; j < V; ++j) rank += (s_selt[j] < ti);
        s_sorted[rank] = ti;
    }
    __syncthreads();
    if (tid < E_) {
        int valid = (tid < V) ? 1 : 0;
        int t     = valid ? s_sorted[tid] : 0;
        ws_times[b * E_ + tid]  = t;
        ws_valid[b * E_ + tid]  = valid;
        out_times[b * E_ + tid] = (float)t;
        out_valid[b * E_ + tid] = (float)valid;
    }
}

// ---------------------------------------------------------------------------
// Kernel 2: split-K GEMM with gather + in-kernel deterministic reduction.
// 256 blocks (XCD-swizzled): tile 64x64, K-chunk 320 (10 x BK=32), LDS dbuf.
// Last block per tile (completion counter) sums KS partials in fixed order
// + bias + time_embed -> out.
// ---------------------------------------------------------------------------
#define BM 64
#define BN 64
#define BK 32
#define PAD 4

__global__ __launch_bounds__(256) void k_gemm_fused(
    const float* __restrict__ h_seq, const float* __restrict__ ent,
    const float* __restrict__ W, const float* __restrict__ bias,
    const float* __restrict__ temb,
    const int* __restrict__ ws_times, const int* __restrict__ ws_valid,
    int* __restrict__ ws_cnt, float* __restrict__ part,
    float* __restrict__ out)
{
    __shared__ float As[2][BK][BM + PAD];
    __shared__ float Bs[2][BK][BN + PAD];
    __shared__ int s_old;

    const int tid = threadIdx.x;
    const int flat  = blockIdx.x;          // 0..255
    const int xcd   = flat & 7;
    const int idx   = flat >> 3;           // 0..31
    const int combo = xcd * 8 + (idx >> 2);// 0..63 -> (col-tile, k-slice)
    const int xr    = idx & 3;             // row tile 0..3
    const int yc    = combo & 15;          // col tile 0..15
    const int zs    = combo >> 4;          // k-slice 0..3

    const int row0 = xr * BM;
    const int col0 = yc * BN;
    const int f0   = zs * KCH;
    const int tile = xr * 16 + yc;

    size_t a_baseh[2], a_basee[2], b_base[2];
    float  a_v[2];
    int    l_row[2], l_f4[2];
    #pragma unroll
    for (int i = 0; i < 2; ++i) {
        int idx2 = tid + i * 256;          // 0..511
        int row = idx2 >> 3, f4 = idx2 & 7;
        l_row[i] = row; l_f4[i] = f4;
        int grow = row0 + row;
        int t    = ws_times[grow];
        a_v[i]   = (float)ws_valid[grow];
        int bb   = grow >> 5;
        a_baseh[i] = ((size_t)bb * T_ + t) * D_   + f4 * 4;
        a_basee[i] = ((size_t)bb * T_ + t) * DENT + f4 * 4;
        b_base[i]  = (size_t)(col0 + row) * F_ + f4 * 4;
    }

    const int rg = tid >> 4;
    const int cg = tid & 15;

    float4 ra[2], rb[2];
    float acc[4][4] = {};

#define LOAD_TILE(KC) do {                                                   \
    int fbase = f0 + (KC) * BK;                                              \
    _Pragma("unroll")                                                        \
    for (int i = 0; i < 2; ++i) {                                            \
        if (fbase < D_) ra[i] = *(const float4*)(h_seq + a_baseh[i] + fbase);\
        else            ra[i] = *(const float4*)(ent + a_basee[i] + (fbase - D_)); \
        rb[i] = *(const float4*)(W + b_base[i] + fbase);                     \
    } } while (0)

#define STORE_TILE(BUF) do {                                                 \
    _Pragma("unroll")                                                        \
    for (int i = 0; i < 2; ++i) {                                            \
        int f = l_f4[i] * 4, r = l_row[i];                                   \
        float v = a_v[i];                                                    \
        As[BUF][f + 0][r] = ra[i].x * v;                                     \
        As[BUF][f + 1][r] = ra[i].y * v;                                     \
        As[BUF][f + 2][r] = ra[i].z * v;                                     \
        As[BUF][f + 3][r] = ra[i].w * v;                                     \
        Bs[BUF][f + 0][r] = rb[i].x;                                         \
        Bs[BUF][f + 1][r] = rb[i].y;                                         \
        Bs[BUF][f + 2][r] = rb[i].z;                                         \
        Bs[BUF][f + 3][r] = rb[i].w;                                         \
    } } while (0)

    LOAD_TILE(0);
    STORE_TILE(0);
    __syncthreads();

    const int NIT = KCH / BK;   // 10
    for (int kc = 0; kc < NIT; ++kc) {
        const int cur = kc & 1;
        if (kc < NIT - 1) LOAD_TILE(kc + 1);
        #pragma unroll
        for (int ff = 0; ff < BK; ++ff) {
            const float4 av = *(const float4*)&As[cur][ff][rg * 4];
            const float4 bv = *(const float4*)&Bs[cur][ff][cg * 4];
            acc[0][0] = fmaf(av.x, bv.x, acc[0][0]);
            acc[0][1] = fmaf(av.x, bv.y, acc[0][1]);
            acc[0][2] = fmaf(av.x, bv.z, acc[0][2]);
            acc[0][3] = fmaf(av.x, bv.w, acc[0][3]);
            acc[1][0] = fmaf(av.y, bv.x, acc[1][0]);
            acc[1][1] = fmaf(av.y, bv.y, acc[1][1]);
            acc[1][2] = fmaf(av.y, bv.z, acc[1][2]);
            acc[1][3] = fmaf(av.y, bv.w, acc[1][3]);
            acc[2][0] = fmaf(av.z, bv.x, acc[2][0]);
            acc[2][1] = fmaf(av.z, bv.y, acc[2][1]);
            acc[2][2] = fmaf(av.z, bv.z, acc[2][2]);
            acc[2][3] = fmaf(av.z, bv.w, acc[2][3]);
            acc[3][0] = fmaf(av.w, bv.x, acc[3][0]);
            acc[3][1] = fmaf(av.w, bv.y, acc[3][1]);
            acc[3][2] = fmaf(av.w, bv.z, acc[3][2]);
            acc[3][3] = fmaf(av.w, bv.w, acc[3][3]);
        }
        if (kc < NIT - 1) { STORE_TILE(cur ^ 1); __syncthreads(); }
    }
#undef LOAD_TILE
#undef STORE_TILE

    // ---- write partial slice ----
    float* pout = part + (size_t)zs * (B_ * E_ * D_);
    #pragma unroll
    for (int j = 0; j < 4; ++j) {
        int grow = row0 + rg * 4 + j;
        *(float4*)(pout + (size_t)grow * D_ + col0 + cg * 4) =
            make_float4(acc[j][0], acc[j][1], acc[j][2], acc[j][3]);
    }

    // ---- completion counter; last block per tile reduces ----
    __threadfence();
    __syncthreads();
    if (tid == 0) s_old = atomicAdd(&ws_cnt[tile], 1);
    __syncthreads();
    if (s_old == KS - 1) {
        __threadfence();
        const int cbase = col0 + cg * 4;
        const float4 bi = *(const float4*)(bias + cbase);
        #pragma unroll
        for (int j = 0; j < 4; ++j) {
            int grow = row0 + rg * 4 + j;
            float4 s = make_float4(0.f, 0.f, 0.f, 0.f);
            #pragma unroll
            for (int k = 0; k < KS; ++k) {   // fixed order -> deterministic
                const float4 pv = *(const float4*)(part
                    + (size_t)k * (B_ * E_ * D_) + (size_t)grow * D_ + cbase);
                s.x += pv.x; s.y += pv.y; s.z += pv.z; s.w += pv.w;
            }
            int t  = ws_times[grow];
            int tc = t < (TVOCAB - 1) ? t : (TVOCAB - 1);
            const float4 te = *(const float4*)(temb + (size_t)tc * D_ + cbase);
            s.x += bi.x + te.x; s.y += bi.y + te.y;
            s.z += bi.z + te.z; s.w += bi.w + te.w;
            *(float4*)(out + (size_t)grow * D_ + cbase) = s;
        }
    }
}

// ---------------------------------------------------------------------------
// Fallback single-kernel GEMM (if ws too small) — known-good round-1 code.
// ---------------------------------------------------------------------------
__global__ __launch_bounds__(256) void k_gemm_full(
    const float* __restrict__ h_seq, const float* __restrict__ ent,
    const float* __restrict__ W, const float* __restrict__ bias,
    const float* __restrict__ temb,
    const int* __restrict__ ws_times, const int* __restrict__ ws_valid,
    float* __restrict__ out)
{
    __shared__ float As[BK][BM + PAD];
    __shared__ float Bs[BK][BN + PAD];

    const int tid  = threadIdx.x;
    const int row0 = blockIdx.x * BM;
    const int col0 = blockIdx.y * BN;

    size_t a_baseh[2], a_basee[2], b_base[2];
    float  a_v[2];
    int    l_row[2], l_f4[2];
    #pragma unroll
    for (int i = 0; i < 2; ++i) {
        int idx = tid + i * 256;
        int row = idx >> 3, f4 = idx & 7;
        l_row[i] = row; l_f4[i] = f4;
        int grow = row0 + row;
        int t    = ws_times[grow];
        a_v[i]   = (float)ws_valid[grow];
        int bb   = grow >> 5;
        a_baseh[i] = ((size_t)bb * T_ + t) * D_   + f4 * 4;
        a_basee[i] = ((size_t)bb * T_ + t) * DENT + f4 * 4;
        b_base[i]  = (size_t)(col0 + row) * F_ + f4 * 4;
    }

    const int rg = tid >> 4;
    const int cg = tid & 15;
    float acc[4][4] = {};

    for (int kc = 0; kc < F_ / BK; ++kc) {
        const int fbase = kc * BK;
        #pragma unroll
        for (int i = 0; i < 2; ++i) {
            float4 val;
            if (fbase < D_) val = *(const float4*)(h_seq + a_baseh[i] + fbase);
            else            val = *(const float4*)(ent + a_basee[i] + (fbase - D_));
            float v = a_v[i];
            int f = l_f4[i] * 4, r = l_row[i];
            As[f + 0][r] = val.x * v;
            As[f + 1][r] = val.y * v;
            As[f + 2][r] = val.z * v;
            As[f + 3][r] = val.w * v;
            float4 wv = *(const float4*)(W + b_base[i] + fbase);
            Bs[f + 0][r] = wv.x;
            Bs[f + 1][r] = wv.y;
            Bs[f + 2][r] = wv.z;
            Bs[f + 3][r] = wv.w;
        }
        __syncthreads();
        #pragma unroll
        for (int ff = 0; ff < BK; ++ff) {
            const float4 av = *(const float4*)&As[ff][rg * 4];
            const float4 bv = *(const float4*)&Bs[ff][cg * 4];
            #pragma unroll
            for (int j = 0; j < 4; ++j) {
                float a = (&av.x)[j];
                acc[j][0] = fmaf(a, bv.x, acc[j][0]);
                acc[j][1] = fmaf(a, bv.y, acc[j][1]);
                acc[j][2] = fmaf(a, bv.z, acc[j][2]);
                acc[j][3] = fmaf(a, bv.w, acc[j][3]);
            }
        }
        __syncthreads();
    }

    const int cbase = col0 + cg * 4;
    const float4 bi = *(const float4*)(bias + cbase);
    #pragma unroll
    for (int j = 0; j < 4; ++j) {
        int grow = row0 + rg * 4 + j;
        int t    = ws_times[grow];
        int tc   = t < (TVOCAB - 1) ? t : (TVOCAB - 1);
        const float4 te = *(const float4*)(temb + (size_t)tc * D_ + cbase);
        float4 o;
        o.x = acc[j][0] + bi.x + te.x;
        o.y = acc[j][1] + bi.y + te.y;
        o.z = acc[j][2] + bi.z + te.z;
        o.w = acc[j][3] + bi.w + te.w;
        *(float4*)(out + (size_t)grow * D_ + cbase) = o;
    }
}

// ---------------------------------------------------------------------------
extern "C" void kernel_launch(void* const* d_in, const int* in_sizes, int n_in,
                              void* d_out, int out_size, void* d_ws, size_t ws_size,
                              hipStream_t stream)
{
    const float* h_seq = (const float*)d_in[0];
    const float* z     = (const float*)d_in[1];
    const float* ent   = (const float*)d_in[2];
    const float* W     = (const float*)d_in[3];
    const float* bias  = (const float*)d_in[4];
    const float* temb  = (const float*)d_in[5];

    float* out       = (float*)d_out;
    float* out_tape  = out;                                // 262144
    float* out_valid = out + (size_t)B_ * E_ * D_;         // 256
    float* out_times = out_valid + B_ * E_;                // 256

    // ws layout: [0] times (256 int) | [1KB] valid (256 int)
    //            [2KB] split-K counters (64 int) | [4KB] partials (4 MB)
    int*   ws_times = (int*)d_ws;
    int*   ws_valid = (int*)((char*)d_ws + 1024);
    int*   ws_cnt   = (int*)((char*)d_ws + 2048);
    float* part     = (float*)((char*)d_ws + 4096);

    k_select<<<B_, 1024, 0, stream>>>(z, ws_times, ws_valid, ws_cnt,
                                      out_valid, out_times);

    const size_t need = 4096 + (size_t)KS * B_ * E_ * D_ * sizeof(float);
    if (ws_size >= need) {
        k_gemm_fused<<<256, 256, 0, stream>>>(h_seq, ent, W, bias, temb,
                                              ws_times, ws_valid, ws_cnt,
                                              part, out_tape);
    } else {
        dim3 g2((B_ * E_) / BM, D_ / BN);
        k_gemm_full<<<g2, 256, 0, stream>>>(h_seq, ent, W, bias, temb,
                                            ws_times, ws_valid, out_tape);
    }
}